// Round 7
// baseline (192.385 us; speedup 1.0000x reference)
//
#include <hip/hip_runtime.h>
#include <math.h>

#define Bb 256
#define Tt 256
#define Ee 384
#define Hh 64

typedef __attribute__((ext_vector_type(8))) short bf16x8;
typedef __attribute__((ext_vector_type(4))) float f32x4;

__device__ inline short f2bf(float f) {
    unsigned u = __float_as_uint(f);
    u += 0x7FFFu + ((u >> 16) & 1);      // RNE
    return (short)(u >> 16);
}
__device__ inline float bf2f(short s) {
    return __uint_as_float(((unsigned)(unsigned short)s) << 16);
}

#define MFMA16(a, b, c) __builtin_amdgcn_mfma_f32_16x16x32_bf16((a), (b), (c), 0, 0, 0)

// ---- ws layout (bytes); total 42,237,952 ----
#define W_HI_OFF 0
#define W_LO_OFF 147456
#define QHI_OFF  294912                      // [B][256][64] bf16, 32768 B/batch
#define QLO_OFF  (QHI_OFF + 8388608)
#define KHI_OFF  (QLO_OFF + 8388608)
#define KLO_OFF  (KHI_OFF + 8388608)
#define VT_OFF   (KLO_OFF + 8388608)         // [B][64][256] bf16 (V transposed)

// ============ prep kernel: W -> bf16 hi/lo in B-fragment layout ============
__global__ __launch_bounds__(256) void prep_w(
    const float* __restrict__ Wq, const float* __restrict__ Wk,
    const float* __restrict__ Wv, unsigned char* __restrict__ wsp)
{
    int u = blockIdx.x * 256 + threadIdx.x;    // 9216 units
    if (u >= 9216) return;
    int frag = u >> 6;                          // ec*12 + tct
    int lu   = u & 63;
    int ec   = frag / 12, tct = frag - ec * 12;
    int koct = lu >> 4, n = lu & 15;
    int col  = tct * 16 + n;
    const float* Wm = (col < 64) ? Wq : ((col < 128) ? Wk : Wv);
    int c = col & 63;
    bf16x8 hi8, lo8;
    #pragma unroll
    for (int j = 0; j < 8; ++j) {
        float v = Wm[(ec * 32 + koct * 8 + j) * 64 + c];
        short h = f2bf(v);
        hi8[j] = h;
        lo8[j] = f2bf(v - bf2f(h));
    }
    *reinterpret_cast<bf16x8*>(wsp + W_HI_OFF + frag * 1024 + lu * 16) = hi8;
    *reinterpret_cast<bf16x8*>(wsp + W_LO_OFF + frag * 1024 + lu * 16) = lo8;
}

// ============ QKV GEMM: 512 blocks x 512 thr, block = (batch, 128-row half) ============
// LDS: phase A staging hi@0 (8KB) lo@8192 (8KB); epilogue bounce reuses 0..49663.
__global__ __launch_bounds__(512) void qkv_gemm(
    const float* __restrict__ x,
    const float* __restrict__ bq, const float* __restrict__ bk,
    const float* __restrict__ bv,
    unsigned char* __restrict__ wsp)
{
    __shared__ __align__(16) unsigned char smem[49664];

    const int blk  = blockIdx.x;
    const int b    = blk >> 1, half = blk & 1;
    const int tid  = threadIdx.x;     // 0..511
    const int w    = tid >> 6;        // 0..7
    const int lane = tid & 63;
    const int quad = lane >> 4, nl = lane & 15;
    const int ri   = w >> 2;          // rowtiles 4ri..4ri+3 (rows 64ri..64ri+63 of half)
    const int cj   = w & 3;           // coltiles 3cj..3cj+2

    f32x4 acc[4][3];
    #pragma unroll
    for (int i = 0; i < 4; ++i)
        #pragma unroll
        for (int j = 0; j < 3; ++j) acc[i][j] = (f32x4){0,0,0,0};

    const float4* x4 = reinterpret_cast<const float4*>(x) + (size_t)b * (Tt * Ee / 4);
    // A staging: dest=tid*16; unit -> rowtile=tid>>6, koct=(tid>>4)&3, row16=tid&15
    const int At  = ((tid >> 6) << 4) + (tid & 15);           // row 0..127 in half
    const int Ako = (tid >> 4) & 3;
    const float4* xsrc = x4 + (size_t)(half * 128 + At) * 96 + Ako * 2;

    float4 pa0 = xsrc[0], pa1 = xsrc[1];

    for (int ec = 0; ec < 12; ++ec) {
        __syncthreads();   // prev readers done
        {
            float v[8] = {pa0.x, pa0.y, pa0.z, pa0.w, pa1.x, pa1.y, pa1.z, pa1.w};
            bf16x8 hi8, lo8;
            #pragma unroll
            for (int j = 0; j < 8; ++j) {
                short h = f2bf(v[j]);
                hi8[j] = h;
                lo8[j] = f2bf(v[j] - bf2f(h));
            }
            *reinterpret_cast<bf16x8*>(smem + tid * 16) = hi8;
            *reinterpret_cast<bf16x8*>(smem + 8192 + tid * 16) = lo8;
        }
        __syncthreads();
        if (ec < 11) { pa0 = xsrc[(ec + 1) * 8]; pa1 = xsrc[(ec + 1) * 8 + 1]; }

        bf16x8 bh[3], bl[3];
        #pragma unroll
        for (int ct = 0; ct < 3; ++ct) {
            size_t o = (size_t)(ec * 12 + cj * 3 + ct) * 1024 + lane * 16;
            bh[ct] = *reinterpret_cast<const bf16x8*>(wsp + W_HI_OFF + o);
            bl[ct] = *reinterpret_cast<const bf16x8*>(wsp + W_LO_OFF + o);
        }
        #pragma unroll
        for (int rt = 0; rt < 4; ++rt) {
            int ao = (4 * ri + rt) * 1024 + lane * 16;
            bf16x8 ah = *reinterpret_cast<bf16x8*>(smem + ao);
            bf16x8 al = *reinterpret_cast<bf16x8*>(smem + ao + 8192);
            #pragma unroll
            for (int ct = 0; ct < 3; ++ct) {
                acc[rt][ct] = MFMA16(ah, bh[ct], acc[rt][ct]);
                acc[rt][ct] = MFMA16(al, bh[ct], acc[rt][ct]);
                acc[rt][ct] = MFMA16(ah, bl[ct], acc[rt][ct]);
            }
        }
    }
    __syncthreads();   // staging dead; bounce region live

    // bias fold
    #pragma unroll
    for (int ct = 0; ct < 3; ++ct) {
        int col = (cj * 3 + ct) * 16 + nl;
        float bias = (col < 64) ? bq[col] : (col < 128 ? bk[col - 64] : bv[col - 128]);
        #pragma unroll
        for (int rt = 0; rt < 4; ++rt)
            #pragma unroll
            for (int r = 0; r < 4; ++r) acc[rt][ct][r] += bias;
    }

    // ---- pass 1: Q bounce (hi@0, lo@16384; row-major [128][64] bf16) ----
    #pragma unroll
    for (int ct = 0; ct < 3; ++ct) {
        int col = (cj * 3 + ct) * 16 + nl;
        if (col < 64) {
            #pragma unroll
            for (int rt = 0; rt < 4; ++rt)
                #pragma unroll
                for (int r = 0; r < 4; ++r) {
                    float val = acc[rt][ct][r];
                    int s = ri * 64 + rt * 16 + quad * 4 + r;
                    short hi = f2bf(val);
                    short lo = f2bf(val - bf2f(hi));
                    *reinterpret_cast<short*>(smem + s * 128 + col * 2) = hi;
                    *reinterpret_cast<short*>(smem + 16384 + s * 128 + col * 2) = lo;
                }
        }
    }
    __syncthreads();
    #pragma unroll
    for (int i = 0; i < 4; ++i) {       // 2048 x 16B
        int u = tid + i * 512;
        int sec = u >> 10, uu = u & 1023;
        bf16x8 d = *reinterpret_cast<bf16x8*>(smem + u * 16);
        size_t g = (sec ? QLO_OFF : QHI_OFF) + (size_t)b * 32768 + half * 16384 + (size_t)uu * 16;
        *reinterpret_cast<bf16x8*>(wsp + g) = d;
    }
    __syncthreads();

    // ---- pass 2: K bounce (hi@0, lo@16384) + V^T bounce (@32768, stride 264B) ----
    #pragma unroll
    for (int ct = 0; ct < 3; ++ct) {
        int col = (cj * 3 + ct) * 16 + nl;
        #pragma unroll
        for (int rt = 0; rt < 4; ++rt)
            #pragma unroll
            for (int r = 0; r < 4; ++r) {
                float val = acc[rt][ct][r];
                int s = ri * 64 + rt * 16 + quad * 4 + r;
                if (col >= 64 && col < 128) {
                    int h = col - 64;
                    short hi = f2bf(val);
                    short lo = f2bf(val - bf2f(hi));
                    *reinterpret_cast<short*>(smem + s * 128 + h * 2) = hi;
                    *reinterpret_cast<short*>(smem + 16384 + s * 128 + h * 2) = lo;
                } else if (col >= 128) {
                    int h = col - 128;
                    *reinterpret_cast<short*>(smem + 32768 + h * 264 + s * 2) = f2bf(val);
                }
            }
    }
    __syncthreads();
    #pragma unroll
    for (int i = 0; i < 6; ++i) {       // K 2048 + Vt 1024 units
        int u = tid + i * 512;
        bf16x8 d;
        size_t g;
        if (u < 2048) {
            int sec = u >> 10, uu = u & 1023;
            d = *reinterpret_cast<bf16x8*>(smem + u * 16);
            g = (sec ? KLO_OFF : KHI_OFF) + (size_t)b * 32768 + half * 16384 + (size_t)uu * 16;
        } else {
            int uv = u - 2048, h = uv >> 4, oct = uv & 15;
            d = *reinterpret_cast<bf16x8*>(smem + 32768 + h * 264 + oct * 16);
            g = VT_OFF + (size_t)b * 32768 + (size_t)h * 512 + half * 256 + oct * 16;
        }
        *reinterpret_cast<bf16x8*>(wsp + g) = d;
    }
}

// ============ attention kernel: 256 blocks x 1024 ============
// LDS: K_HI 0 (32KB), K_LO 32768, VF 65536 (32KB), P-bufs 98304 (21504) = 119808
#define K_HI 0
#define K_LO 32768
#define VF   65536
#define PBASE 98304
__global__ __launch_bounds__(1024) void attn(
    const unsigned char* __restrict__ wsp, float* __restrict__ out)
{
    __shared__ __align__(16) unsigned char smem[119808];

    const int b    = blockIdx.x;
    const int tid  = threadIdx.x;
    const int w    = tid >> 6;
    const int lane = tid & 63;
    const int quad = lane >> 4, nl = lane & 15;
    const int t0   = w * 16;

    const unsigned char* qhi_b = wsp + QHI_OFF + (size_t)b * 32768;
    const unsigned char* qlo_b = wsp + QLO_OFF + (size_t)b * 32768;
    const unsigned char* khi_b = wsp + KHI_OFF + (size_t)b * 32768;
    const unsigned char* klo_b = wsp + KLO_OFF + (size_t)b * 32768;
    const unsigned char* vt_b  = wsp + VT_OFF  + (size_t)b * 32768;

    // stage K frags: 64 tasks (st,ks,lo), lane-linear LDS writes
    #pragma unroll
    for (int i = 0; i < 4; ++i) {
        int t = w + i * 16;
        int st = t & 15, ks = (t >> 4) & 1, lo = t >> 5;
        const unsigned char* src = (lo ? klo_b : khi_b)
            + (size_t)(st * 16 + nl) * 128 + ks * 64 + quad * 16;
        bf16x8 d = *reinterpret_cast<const bf16x8*>(src);
        *reinterpret_cast<bf16x8*>(smem + (lo ? K_LO : K_HI) + (st * 2 + ks) * 1024 + lane * 16) = d;
    }
    // stage V frags: 32 tasks (p,nt)
    #pragma unroll
    for (int i = 0; i < 2; ++i) {
        int t = w + i * 16;
        int p = t >> 2, nt = t & 3;
        const unsigned char* src = vt_b + (size_t)(nt * 16 + nl) * 512 + (p * 32 + quad * 8) * 2;
        bf16x8 d = *reinterpret_cast<const bf16x8*>(src);
        *reinterpret_cast<bf16x8*>(smem + VF + (p * 4 + nt) * 1024 + lane * 16) = d;
    }
    // Q frags to registers (row-major, coalesced)
    bf16x8 qh0 = *reinterpret_cast<const bf16x8*>(qhi_b + (size_t)(t0 + nl) * 128 + quad * 16);
    bf16x8 qh1 = *reinterpret_cast<const bf16x8*>(qhi_b + (size_t)(t0 + nl) * 128 + 64 + quad * 16);
    bf16x8 ql0 = *reinterpret_cast<const bf16x8*>(qlo_b + (size_t)(t0 + nl) * 128 + quad * 16);
    bf16x8 ql1 = *reinterpret_cast<const bf16x8*>(qlo_b + (size_t)(t0 + nl) * 128 + 64 + quad * 16);
    __syncthreads();

    // ---- causal attention, wave w owns rows 16w..16w+15 (verified loop) ----
    f32x4 oacc[4];
    #pragma unroll
    for (int i = 0; i < 4; ++i) oacc[i] = (f32x4){0,0,0,0};
    float lsum = 0.f;
    unsigned char* pb = smem + PBASE + w * 1344;
    const int npairs = (w >> 1) + 1;

    for (int p = 0; p < npairs; ++p) {
        #pragma unroll
        for (int hf = 0; hf < 2; ++hf) {
            int st = 2 * p + hf;
            f32x4 s0 = (f32x4){0,0,0,0}, s1 = (f32x4){0,0,0,0};
            int kb = st * 2048 + lane * 16;
            bf16x8 kh0 = *reinterpret_cast<bf16x8*>(smem + K_HI + kb);
            bf16x8 kh1 = *reinterpret_cast<bf16x8*>(smem + K_HI + kb + 1024);
            bf16x8 kl0 = *reinterpret_cast<bf16x8*>(smem + K_LO + kb);
            bf16x8 kl1 = *reinterpret_cast<bf16x8*>(smem + K_LO + kb + 1024);
            s0 = MFMA16(qh0, kh0, s0);
            s1 = MFMA16(qh1, kh1, s1);
            s0 = MFMA16(ql0, kh0, s0);
            s1 = MFMA16(ql1, kh1, s1);
            s0 = MFMA16(qh0, kl0, s0);
            s1 = MFMA16(qh1, kl1, s1);
            int sg = st * 16 + nl;
            #pragma unroll
            for (int r = 0; r < 4; ++r) {
                int tg = t0 + quad * 4 + r;
                float sv = s0[r] + s1[r];
                float pv = (sg <= tg) ? __expf(sv) : 0.f;
                *reinterpret_cast<short*>(pb + ((quad * 4 + r) * 40 + hf * 16 + nl) * 2) = f2bf(pv);
            }
        }
        asm volatile("s_waitcnt lgkmcnt(0)" ::: "memory");
        bf16x8 pa = *reinterpret_cast<bf16x8*>(pb + (nl * 40 + quad * 8) * 2);
        float ls = 0.f;
        #pragma unroll
        for (int j = 0; j < 8; ++j) ls += bf2f(pa[j]);
        ls += __shfl_xor(ls, 16);
        ls += __shfl_xor(ls, 32);
        lsum += ls;
        int vb = p * 4096 + lane * 16;
        #pragma unroll
        for (int nt = 0; nt < 4; ++nt) {
            bf16x8 vf = *reinterpret_cast<bf16x8*>(smem + VF + vb + nt * 1024);
            oacc[nt] = MFMA16(pa, vf, oacc[nt]);
        }
    }

    float* lb_ = reinterpret_cast<float*>(pb + 1280);
    if (lane < 16) lb_[lane] = lsum;
    asm volatile("s_waitcnt lgkmcnt(0)" ::: "memory");
    float* ob = out + (size_t)b * Tt * Hh + (size_t)t0 * Hh;
    #pragma unroll
    for (int r = 0; r < 4; ++r) {
        float inv = 1.0f / lb_[quad * 4 + r];
        #pragma unroll
        for (int nt = 0; nt < 4; ++nt)
            ob[(quad * 4 + r) * 64 + nt * 16 + nl] = oacc[nt][r] * inv;
    }
}

extern "C" void kernel_launch(void* const* d_in, const int* in_sizes, int n_in,
                              void* d_out, int out_size, void* d_ws, size_t ws_size,
                              hipStream_t stream) {
    const float* x  = (const float*)d_in[0];
    const float* Wq = (const float*)d_in[1];
    const float* bq = (const float*)d_in[2];
    const float* Wk = (const float*)d_in[3];
    const float* bk = (const float*)d_in[4];
    const float* Wv = (const float*)d_in[5];
    const float* bv = (const float*)d_in[6];
    float* out = (float*)d_out;
    unsigned char* wsp = (unsigned char*)d_ws;   // needs 42,237,952 B
    hipLaunchKernelGGL(prep_w,   dim3(36),  dim3(256),  0, stream, Wq, Wk, Wv, wsp);
    hipLaunchKernelGGL(qkv_gemm, dim3(512), dim3(512),  0, stream, x, bq, bk, bv, wsp);
    hipLaunchKernelGGL(attn,     dim3(Bb),  dim3(1024), 0, stream, wsp, out);
}